// Round 4
// baseline (298.896 us; speedup 1.0000x reference)
//
#include <hip/hip_runtime.h>

#define SEQ   256
#define FEAT  768
#define FILT  6
#define WELEMS (2304 * FILT)       // 13824 floats per s

typedef _Float16 f16x8 __attribute__((ext_vector_type(8)));  // MFMA A/B frag
typedef __attribute__((ext_vector_type(4))) float f32x4;     // MFMA C/D

// R9: 2-term f16 split. R8 (~97us est; fell out of rocprof top-5 under the
// 119us harness memsets) proved the mod-3 phasing: miss traffic is now ~x
// read-once (~210 MB -> 33-48us service floor). Remaining 2x gap is per-step
// critical path + latency. Changes vs R8:
//  - x = xh + xl (exact f16 pair), W -> f16 RTN once at staging. Error is
//    W-rounding only: sigma ~2.7e-4, absmax ~1.5e-3 << 0.0078 passing now.
//    Per K-step: 3->2 MFMA, 2->1 ds_read_b128, ~40->~28 cvt VALU.
//  - LDS W table 54 -> 27 KB.
//  - A-prefetch depth 4 -> 6 (12 dwordx4 in flight/wave).
//  - dropped the cv?frag:zero selects: B garbage in lanes col>=6 corrupts
//    only D cols >=6 (never stored); invalid lanes clamp addr in-bounds.
// Kept: per-s skinny GEMM out[256b,6o] = win[256b,2304k] @ W[2304k,6o] via
// mfma_f32_16x16x32_f16 (A/B share the (h,e)->k bijection, HW-verified by
// R7/R8 passing); C/D col=lane&15, row=4*(lane>>4)+reg; XCD-contiguous s
// swizzle; mod-3 band phasing (row r read by all consumers in phase r%3);
// grid 512 = (s, batch half), 8 waves x 16-batch M-tiles.
__global__ __launch_bounds__(512, 4)
void pos_linear_kernel(const float* __restrict__ x,
                       const float* __restrict__ W,
                       const float* __restrict__ bias,
                       float* __restrict__ out) {
    // f16 frag for k-step t, k-group h, col c: shorts[((4t+h)*6 + c)*8 + e]
    __shared__ __align__(16) unsigned short wf[13824];

    const int blk   = blockIdx.x;
    const int halfb = blk >> 8;                     // batch half 0/1
    const int sb    = blk & 255;
    const int s     = ((sb & 7) << 5) | (sb >> 3);  // XCD-contiguous s ranges
    const int tid   = threadIdx.x;

    // ---- Stage W[s] -> f16 fragments in LDS (one-time, RTN convert) ----
    {
        const float* Ws = W + (size_t)s * WELEMS;
        for (int k = tid; k < 2304; k += 512) {
            const int slot8 = (k >> 3) * 6;         // (4t+h)*6
            const int e     = k & 7;
            #pragma unroll
            for (int o = 0; o < FILT; ++o) {
                _Float16 hv = (_Float16)Ws[k * FILT + o];
                wf[(slot8 + o) * 8 + e] = *(const unsigned short*)&hv;
            }
        }
    }
    __syncthreads();

    const int lane = tid & 63;
    const int wave = tid >> 6;        // 0..7
    const int row  = lane & 15;       // batch within M-tile (A side)
    const int h    = lane >> 4;       // k-group 0..3
    const int col  = lane & 15;       // output col (valid < 6, B side)
    const bool cv  = col < FILT;
    const int b0   = (halfb << 7) + (wave << 4);    // tile batch base

    // invalid lanes clamp to col 5: in-bounds garbage -> D cols >=6 only
    const int bidx = (6 * h + (cv ? col : 5)) * 8;  // B-frag short base

    f32x4 acc_h = {0, 0, 0, 0};
    f32x4 acc_l = {0, 0, 0, 0};

    // per-lane x base: batch (b0+row), feature offset 8h; band adds r*FEAT
    const float* xb = x + (size_t)(b0 + row) * (SEQ * FEAT) + 8 * h;

    // one K-step: split 8 floats -> f16 hi/lo frags, read B frag, 2 MFMA
    auto step = [&](f32x4 u, f32x4 v, int tg) {
        f16x8 ah, al;
        #pragma unroll
        for (int e = 0; e < 8; ++e) {
            float f = (e < 4) ? u[e] : v[e - 4];
            _Float16 hh = (_Float16)f;              // RTN
            ah[e] = hh;
            al[e] = (_Float16)(f - (float)hh);      // exact residual -> f16
        }
        f16x8 bw = *(const f16x8*)&wf[bidx + 192 * tg];
        acc_h = __builtin_amdgcn_mfma_f32_16x16x32_f16(ah, bw, acc_h, 0, 0, 0);
        acc_l = __builtin_amdgcn_mfma_f32_16x16x32_f16(al, bw, acc_l, 0, 0, 0);
    };

    // 3 phases; phase p handles band w with r = s-1+w, r % 3 == p
    // (w = (p - s + 256) % 3; 256 % 3 == 1). Band skip at edges == zero pad.
    #pragma unroll
    for (int p = 0; p < 3; ++p) {
        const int w = (p - s + 256) % 3;
        const int r = s - 1 + w;
        if (r >= 0 && r < SEQ) {                    // block-uniform
            const f32x4* ap = (const f32x4*)(xb + (size_t)r * FEAT);
            const int tb = 24 * w;

            // depth-6 circular prefetch: 12 dwordx4 in flight per wave
            f32x4 qa[6], qb[6];
            #pragma unroll
            for (int t = 0; t < 6; ++t) { qa[t] = ap[8 * t]; qb[t] = ap[8 * t + 1]; }
            #pragma unroll
            for (int t = 0; t < 24; ++t) {          // full unroll: t%6 static
                f32x4 u = qa[t % 6], v = qb[t % 6];
                if (t + 6 < 24) {
                    qa[t % 6] = ap[8 * (t + 6)];
                    qb[t % 6] = ap[8 * (t + 6) + 1];
                }
                step(u, v, tb + t);
            }
        }
        __syncthreads();   // phase alignment (3 barriers total)
    }

    // C/D: col = lane&15, row = 4*(lane>>4) + reg  [HW-verified mapping]
    if (cv) {
        const float bv = bias[s * FILT + col];
        #pragma unroll
        for (int g = 0; g < 4; ++g) {
            const int b = b0 + 4 * h + g;
            float vsum = acc_h[g] + acc_l[g] + bv;
            vsum = vsum > 0.f ? vsum : 0.f;
            out[((size_t)b * SEQ + s) * FILT + col] = vsum;
        }
    }
}

extern "C" void kernel_launch(void* const* d_in, const int* in_sizes, int n_in,
                              void* d_out, int out_size, void* d_ws, size_t ws_size,
                              hipStream_t stream) {
    const float* x   = (const float*)d_in[0];  // (256, 256, 768) fp32
    const float* W   = (const float*)d_in[1];  // (256, 2304, 6) fp32
    const float* b   = (const float*)d_in[2];  // (256, 6) fp32
    float*       out = (float*)d_out;          // (256, 256, 6) fp32
    (void)in_sizes; (void)n_in; (void)out_size; (void)d_ws; (void)ws_size;
    pos_linear_kernel<<<SEQ * 2, 512, 0, stream>>>(x, W, b, out);
}